// Round 9
// baseline (289.865 us; speedup 1.0000x reference)
//
#include <hip/hip_runtime.h>

#define Bv 1024
#define Tv 512
#define Kv 64
#define LN2   0.69314718055994530942f
#define LOG2E 1.4426950408889634f

typedef short bf16x8 __attribute__((ext_vector_type(8)));
typedef float f32x4  __attribute__((ext_vector_type(4)));

// Verified gfx950 builtin (guide §3 list); short8 operands per guide example.
#define MFMA32(A, B, C) __builtin_amdgcn_mfma_f32_16x16x32_bf16((A), (B), (C), 0, 0, 0)

// NaN/Inf-proof clamp (plain VALU, compiler-visible).
static __device__ __forceinline__ float clampf(float v) {
    return fminf(fmaxf(v, 1.0e-18f), 1.0e18f);
}

// Pure-C bf16 round-to-nearest-even. NO inline asm anywhere: the compiler
// sees every def feeding the MFMA, so it owns all VALU->MFMA hazard nops.
static __device__ __forceinline__ unsigned short bf16rne(float f) {
    unsigned u = __float_as_uint(f);
    return (unsigned short)((u + 0x7FFFu + ((u >> 16) & 1u)) >> 16);
}
static __device__ __forceinline__ bf16x8 pk8(f32x4 lo, f32x4 hi) {
    union { unsigned short us[8]; bf16x8 v; } u;
    #pragma unroll
    for (int j = 0; j < 4; ++j) {
        u.us[j]     = bf16rne(lo[j]);
        u.us[4 + j] = bf16rne(hi[j]);
    }
    return u.v;
}

__global__ __launch_bounds__(128, 1) void crf_fwd_mfma(
    const float* __restrict__ x,      // [B,T,K]
    const int*   __restrict__ y,      // [T,B]
    const float* __restrict__ trans,  // [K,K]
    const float* __restrict__ startv, // [K]
    const float* __restrict__ endv,   // [K]
    float* __restrict__ out_b)        // [B]
{
    __shared__ float Es[Kv * Kv];   // exp(trans)
    __shared__ float TRs[Kv * Kv];  // raw trans (numerator)
    __shared__ float nums[16];

    const int tid = threadIdx.x;
    for (int i = tid; i < Kv * Kv; i += 128) {
        float tv = trans[i];
        TRs[i] = tv;
        Es[i]  = __expf(tv);
    }
    __syncthreads();

    const int wv    = tid >> 6;
    const int lane  = tid & 63;
    const int bbase = blockIdx.x * 16;

    float logZ = 0.f;

    if (wv == 0) {
        // ================= forward-algorithm wave =================
        const int s16 = lane & 15;   // sequence-in-block = A row = B/C col
        const int G   = lane >> 4;

        // Output-state permutation: C[m] row r holds state f(m,r).
        // f(m,r) = 32*(m>>1) + 8*(r>>2) + 4*(m&1) + (r&3)
        // => C[m] reg j (row 4G+j) = state 32*(m>>1)+8G+4*(m&1)+j
        //    = B-slot (kb=m>>1, i=4*(m&1)+j): in-lane handoff.
        bf16x8 ef[4][2];
        #pragma unroll
        for (int m = 0; m < 4; ++m) {
            const int fm = 32 * (m >> 1) + 8 * (s16 >> 2) + 4 * (m & 1) + (s16 & 3);
            #pragma unroll
            for (int kb = 0; kb < 2; ++kb) {
                f32x4 elo, ehi;
                #pragma unroll
                for (int i = 0; i < 4; ++i) {
                    elo[i] = Es[(32 * kb + 8 * G + i) * Kv + fm];
                    ehi[i] = Es[(32 * kb + 8 * G + 4 + i) * Kv + fm];
                }
                ef[m][kb] = pk8(elo, ehi);
            }
        }

        const char* xc = (const char*)x;
        // byte offset of x[bbase+s16][t=0][8G]
        unsigned bo = (unsigned)(bbase + s16) * (unsigned)(Tv * Kv * 4) + 32u * G;
        // per-m byte sub-offsets: states 32*(m>>1)+4*(m&1) beyond 8G
        const unsigned offm[4] = {0u, 16u, 128u, 144u};

        // ---- t = 0: W[kb] slot i = exp(start[32kb+8G+i] + x[s][0][...]) ----
        bf16x8 W[2];
        #pragma unroll
        for (int kb = 0; kb < 2; ++kb) {
            f32x4 xa  = *(const f32x4*)(xc + bo + kb * 128u);
            f32x4 xb_ = *(const f32x4*)(xc + bo + kb * 128u + 16u);
            f32x4 sa  = *(const f32x4*)(startv + 32 * kb + 8 * G);
            f32x4 sb  = *(const f32x4*)(startv + 32 * kb + 8 * G + 4);
            f32x4 wa, wb;
            #pragma unroll
            for (int j = 0; j < 4; ++j) {
                wa[j] = __expf(xa[j] + sa[j]);
                wb[j] = __expf(xb_[j] + sb[j]);
            }
            W[kb] = pk8(wa, wb);
        }

        // ---- x ring: slots 0..5 hold x (later q) for steps 1..6 ----
        f32x4 xr[6][4];
        #pragma unroll
        for (int i = 0; i < 6; ++i)
            #pragma unroll
            for (int m = 0; m < 4; ++m)
                xr[i][m] = *(const f32x4*)(xc + bo + (1 + i) * 256u + offm[m]);

        // prologue: convert slot 0 -> q_1 with bias -7
        #pragma unroll
        for (int m = 0; m < 4; ++m)
            #pragma unroll
            for (int j = 0; j < 4; ++j)
                xr[0][m][j] = exp2f(fmaf(xr[0][m][j], LOG2E, -7.f));

        int sigma = 0;          // total log2 scale folded into W
        int bias_pending = -7;  // bias embedded in q of the NEXT consumed slot
        unsigned boR = bo + 7u * 256u;
        const unsigned boMax = bo + 511u * 256u;

#define CRF_STEP(I, IN, CV, RL)                                                  \
        {                                                                        \
            f32x4 C[4];                                                          \
            _Pragma("unroll")                                                    \
            for (int m = 0; m < 4; ++m) {                                        \
                f32x4 acc = {0.f, 0.f, 0.f, 0.f};                                \
                acc = MFMA32(ef[m][0], W[0], acc);                               \
                acc = MFMA32(ef[m][1], W[1], acc);                               \
                C[m] = acc;                                                      \
            }                                                                    \
            /* clamp: NaN/Inf-proof */                                           \
            _Pragma("unroll")                                                    \
            for (int m = 0; m < 4; ++m)                                          \
                _Pragma("unroll")                                                \
                for (int j = 0; j < 4; ++j)                                      \
                    C[m][j] = clampf(C[m][j]);                                   \
            sigma += bias_pending;                                               \
            unsigned cb = (unsigned)__builtin_amdgcn_readfirstlane(              \
                (int)__float_as_uint(C[0][0]));                                  \
            int e = (int)((cb >> 23) & 0xFFu);                                   \
            int corr = (147 - e) >> 3;  /* gain 1/8: damped lag loop */          \
            corr = corr > 4 ? 4 : (corr < -4 ? -4 : corr);                       \
            float bias = (float)(corr - 7);                                      \
            bias_pending = corr - 7;                                             \
            /* in-lane handoff: W'[kb] = C[2kb],C[2kb+1] scaled by q */          \
            f32x4 w0 = C[0] * xr[I][0];                                          \
            f32x4 w1 = C[1] * xr[I][1];                                          \
            f32x4 w2 = C[2] * xr[I][2];                                          \
            f32x4 w3 = C[3] * xr[I][3];                                          \
            W[0] = pk8(w0, w1);                                                  \
            W[1] = pk8(w2, w3);                                                  \
            if (CV) { /* convert next slot's x -> q for step t+1 */              \
                _Pragma("unroll")                                                \
                for (int m = 0; m < 4; ++m)                                      \
                    _Pragma("unroll")                                            \
                    for (int j = 0; j < 4; ++j)                                  \
                        xr[IN][m][j] =                                           \
                            exp2f(fmaf(xr[IN][m][j], LOG2E, bias));              \
            }                                                                    \
            if (RL) { /* reload slot I with x_{t+6} (clamped index) */           \
                unsigned off = boR + (I) * 256u;                                 \
                off = off < boMax ? off : boMax;                                 \
                _Pragma("unroll")                                                \
                for (int m = 0; m < 4; ++m)                                      \
                    xr[I][m] = *(const f32x4*)(xc + off + offm[m]);              \
            }                                                                    \
        }

        // steps 1..510 (85 iterations x 6 steps)
        for (int it = 0; it < 85; ++it) {
            CRF_STEP(0, 1, 1, 1) CRF_STEP(1, 2, 1, 1) CRF_STEP(2, 3, 1, 1)
            CRF_STEP(3, 4, 1, 1) CRF_STEP(4, 5, 1, 1) CRF_STEP(5, 0, 1, 1)
            boR += 6u * 256u;
        }
        // step 511 (its q was converted at step 510)
        CRF_STEP(0, 1, 0, 0)
#undef CRF_STEP

        // logZ_s = log( sum_k W[k][s]*exp(end[k]) ) - LN2*sigma
        float part = 0.f;
        #pragma unroll
        for (int kb = 0; kb < 2; ++kb) {
            union { bf16x8 v; unsigned short us[8]; } u;
            u.v = W[kb];
            #pragma unroll
            for (int i = 0; i < 8; ++i) {
                float wval = __uint_as_float(((unsigned)u.us[i]) << 16);
                part += wval * __expf(endv[32 * kb + 8 * G + i]);
            }
        }
        part += __shfl_xor(part, 16, 64);
        part += __shfl_xor(part, 32, 64);
        part  = fmaxf(part, 1.0e-30f);   // log(<=0) impossible
        logZ  = __logf(part) - LN2 * (float)sigma;
    } else {
        // ================= numerator wave =================
        const int s  = lane & 15;
        const int tg = lane >> 4;         // t-range [tg*128, tg*128+128)
        const int bb = bbase + s;
        const size_t xsb = (size_t)bb * (Tv * Kv);

        float acc = 0.f;
        int yprev = 0;
        if (tg > 0) yprev = y[(tg * 128 - 1) * Bv + bb];

        for (int c = 0; c < 8; ++c) {
            const int t0 = tg * 128 + c * 16;
            int yv[16];
            #pragma unroll
            for (int j = 0; j < 16; ++j) yv[j] = y[(t0 + j) * Bv + bb];
            float xv[16];
            #pragma unroll
            for (int j = 0; j < 16; ++j)
                xv[j] = x[xsb + (size_t)(t0 + j) * Kv + yv[j]];
            #pragma unroll
            for (int j = 0; j < 16; ++j) {
                int yp = (j == 0) ? yprev : yv[j - 1];
                float tr = TRs[yp * Kv + yv[j]];
                acc += xv[j];
                acc += (t0 + j > 0) ? tr : startv[yv[0]];
            }
            yprev = yv[15];
        }
        if (tg == 3) acc += endv[yprev];   // yprev = y[511]

        acc += __shfl_xor(acc, 16, 64);    // sum the 4 t-groups per s
        acc += __shfl_xor(acc, 32, 64);
        if (lane < 16) nums[lane] = acc;
    }

    __syncthreads();
    if (wv == 0 && lane < 16) out_b[bbase + lane] = logZ - nums[lane];
}

__global__ __launch_bounds__(256) void crf_reduce_kernel(
    const float* __restrict__ in, float* __restrict__ out)
{
    const int tid = threadIdx.x;
    float v = 0.f;
    for (int i = tid; i < Bv; i += 256) v += in[i];
    #pragma unroll
    for (int off = 32; off > 0; off >>= 1) v += __shfl_xor(v, off, 64);
    __shared__ float ws[4];
    if ((tid & 63) == 0) ws[tid >> 6] = v;
    __syncthreads();
    if (tid == 0) out[0] = ws[0] + ws[1] + ws[2] + ws[3];
}

extern "C" void kernel_launch(void* const* d_in, const int* in_sizes, int n_in,
                              void* d_out, int out_size, void* d_ws, size_t ws_size,
                              hipStream_t stream) {
    const float* x      = (const float*)d_in[0];
    // d_in[1] = seq_len (all == T; unused by the reference math)
    const int*   y      = (const int*)d_in[2];
    const float* trans  = (const float*)d_in[3];
    const float* startv = (const float*)d_in[4];
    const float* endv   = (const float*)d_in[5];
    float* out = (float*)d_out;
    float* wsb = (float*)d_ws;   // [B] per-sequence results

    hipLaunchKernelGGL(crf_fwd_mfma, dim3(Bv / 16), dim3(128), 0, stream,
                       x, y, trans, startv, endv, wsb);
    hipLaunchKernelGGL(crf_reduce_kernel, dim3(1), dim3(256), 0, stream, wsb, out);
}